// Round 1
// 1017.151 us; speedup vs baseline: 1.5085x; 1.5085x over previous
//
#include <hip/hip_runtime.h>
#include <hip/hip_bf16.h>

// GraphSAGE 4-layer forward.
// R2: bf16 activations everywhere heavy; aggregate-then-GEMM restructure;
//     fused MFMA GEMM (hb@Ws + aggb@Wn + bias -> PReLU -> stats);
//     per-block partial stats (no contended atomics); pooling from fp32.
// R3: k_agg rewritten for MLP: 16-lane groups x dwordx4 loads, 8 edges per
//     wave-iteration (latency-bound -> throughput); k_bnpool grid 512->2048.

#define EPS_BN 1e-5f

typedef __attribute__((ext_vector_type(8))) short bf16x8;
typedef __attribute__((ext_vector_type(4))) float f32x4;

// ---------------- embedding gather -> bf16 h ---------------------------------
__global__ __launch_bounds__(256) void k_embed(const int* __restrict__ feat,
                                               const float* __restrict__ emb,
                                               __hip_bfloat162* __restrict__ hb2, int n) {
  int idx = blockIdx.x * 256 + threadIdx.x;   // one bf16x2 each
  if (idx < n * 64) {
    int i = idx >> 6, c2 = idx & 63;
    float2 v = ((const float2*)emb)[feat[i] * 64 + c2];
    hb2[idx] = __float22bfloat162_rn(v);
  }
}

// ---------------- W -> bf16, transposed: Wt[l][n][k] = W[l][k][n] ------------
__global__ __launch_bounds__(256) void k_wconv(const float* __restrict__ W,
                                               __hip_bfloat16* __restrict__ Wt, int total) {
  int idx = blockIdx.x * 256 + threadIdx.x;
  if (idx < total) {
    int l = idx >> 14, r = idx & 16383, nn = r >> 7, kk = r & 127;
    Wt[idx] = __float2bfloat16(W[(l << 14) + kk * 128 + nn]);
  }
}

// ---------------- degree histogram over dst ----------------------------------
__global__ __launch_bounds__(256) void k_hist(const int* __restrict__ idx,
                                              int* __restrict__ cnt, int m) {
  int e = blockIdx.x * 256 + threadIdx.x;
  if (e < m) atomicAdd(&cnt[idx[e]], 1);
}

// ---------------- per-graph node counts via binary search (gid sorted) -------
__global__ void k_gcount(const int* __restrict__ gid, int* __restrict__ gcnt, int n, int G) {
  int g = blockIdx.x * blockDim.x + threadIdx.x;
  if (g >= G) return;
  int lo0 = 0, hi = n;
  while (lo0 < hi) { int mid = (lo0 + hi) >> 1; if (gid[mid] < g) lo0 = mid + 1; else hi = mid; }
  int lo1 = lo0; hi = n;
  while (lo1 < hi) { int mid = (lo1 + hi) >> 1; if (gid[mid] < g + 1) lo1 = mid + 1; else hi = mid; }
  gcnt[g] = lo1 - lo0;
}

// ---------------- exclusive scan of cnt -> row_ptr (3 kernels) ---------------
__global__ __launch_bounds__(256) void k_scan1(const int* __restrict__ cnt,
                                               int* __restrict__ excl,
                                               int* __restrict__ blk_sums, int n) {
  __shared__ int sh[256];
  int t = threadIdx.x;
  int base = blockIdx.x * 1024 + t * 4;
  int4 v = {0, 0, 0, 0};
  if (base < n) v = *(const int4*)&cnt[base];
  int s = v.x + v.y + v.z + v.w;
  sh[t] = s;
  __syncthreads();
  for (int off = 1; off < 256; off <<= 1) {
    int x = (t >= off) ? sh[t - off] : 0;
    __syncthreads();
    sh[t] += x;
    __syncthreads();
  }
  int ex = sh[t] - s;
  if (t == 255) blk_sums[blockIdx.x] = sh[255];
  if (base < n) {
    excl[base]     = ex;
    excl[base + 1] = ex + v.x;
    excl[base + 2] = ex + v.x + v.y;
    excl[base + 3] = ex + v.x + v.y + v.z;
  }
}

__global__ void k_scan2(int* __restrict__ bs, int nb) {
  __shared__ int sh[128];
  int t = threadIdx.x;
  int v = (t < nb) ? bs[t] : 0;
  sh[t] = v;
  __syncthreads();
  for (int off = 1; off < 128; off <<= 1) {
    int x = (t >= off) ? sh[t - off] : 0;
    __syncthreads();
    sh[t] += x;
    __syncthreads();
  }
  if (t < nb) bs[t] = sh[t] - v;
}

__global__ __launch_bounds__(256) void k_scan3(int* __restrict__ rp, const int* __restrict__ bs,
                                               const int* __restrict__ cnt, int* __restrict__ cursor,
                                               float* __restrict__ deg, int n, int ne) {
  int i = blockIdx.x * 256 + threadIdx.x;
  if (i < n) {
    int r = rp[i] + bs[i >> 10];
    rp[i] = r;
    cursor[i] = r;
    int c = cnt[i];
    deg[i] = (float)(c > 0 ? c : 1);
  }
  if (i == 0) rp[n] = ne;
}

// ---------------- CSR scatter ------------------------------------------------
__global__ __launch_bounds__(256) void k_csr(const int* __restrict__ src, const int* __restrict__ dst,
                                             int* __restrict__ cursor, int* __restrict__ csr_src, int ne) {
  int e = blockIdx.x * 256 + threadIdx.x;
  if (e < ne) {
    int p = atomicAdd(&cursor[dst[e]], 1);
    csr_src[p] = src[e];
  }
}

// ---------------- mean-aggregate bf16 h rows -> bf16 agg ---------------------
// R3: one wave per node; 4 groups of 16 lanes; each lane loads dwordx4 (16B),
// so one group covers a 256B row and the wave processes 4 edges per step,
// unrolled x2 => 8 edges in flight. Cross-group combine via shfl_xor.
__device__ __forceinline__ void acc8(float* a, uint4 v) {
  float2 f;
  f = __bfloat1622float2(*(const __hip_bfloat162*)&v.x); a[0] += f.x; a[1] += f.y;
  f = __bfloat1622float2(*(const __hip_bfloat162*)&v.y); a[2] += f.x; a[3] += f.y;
  f = __bfloat1622float2(*(const __hip_bfloat162*)&v.z); a[4] += f.x; a[5] += f.y;
  f = __bfloat1622float2(*(const __hip_bfloat162*)&v.w); a[6] += f.x; a[7] += f.y;
}

__global__ __launch_bounds__(256) void k_agg(const uint4* __restrict__ hb4,
                                             const int* __restrict__ rp, const int* __restrict__ csr_src,
                                             const float* __restrict__ deg,
                                             uint4* __restrict__ aggb4, int n) {
  int lane = threadIdx.x & 63, wid = threadIdx.x >> 6;
  int g = lane >> 4, lr = lane & 15;
  for (int i = blockIdx.x * 4 + wid; i < n; i += gridDim.x * 4) {
    int beg = rp[i], end = rp[i + 1];
    float a[8];
#pragma unroll
    for (int c = 0; c < 8; ++c) a[c] = 0.f;
    int e = beg;
    for (; e + 8 <= end; e += 8) {        // 8 edges per wave-iteration
      int s0 = csr_src[e + g];
      int s1 = csr_src[e + 4 + g];
      uint4 v0 = hb4[(size_t)s0 * 16 + lr];
      uint4 v1 = hb4[(size_t)s1 * 16 + lr];
      acc8(a, v0);
      acc8(a, v1);
    }
    for (; e + g < end; e += 4) {         // predicated 4-edge tail (<=2 iters)
      int s = csr_src[e + g];
      uint4 v = hb4[(size_t)s * 16 + lr];
      acc8(a, v);
    }
#pragma unroll
    for (int c = 0; c < 8; ++c) {         // combine the 4 groups
      a[c] += __shfl_xor(a[c], 16, 64);
      a[c] += __shfl_xor(a[c], 32, 64);
    }
    if (g == 0) {
      float invd = 1.0f / deg[i];
      __hip_bfloat162 p0 = __float22bfloat162_rn(make_float2(a[0] * invd, a[1] * invd));
      __hip_bfloat162 p1 = __float22bfloat162_rn(make_float2(a[2] * invd, a[3] * invd));
      __hip_bfloat162 p2 = __float22bfloat162_rn(make_float2(a[4] * invd, a[5] * invd));
      __hip_bfloat162 p3 = __float22bfloat162_rn(make_float2(a[6] * invd, a[7] * invd));
      uint4 o;
      o.x = *(unsigned int*)&p0; o.y = *(unsigned int*)&p1;
      o.z = *(unsigned int*)&p2; o.w = *(unsigned int*)&p3;
      aggb4[(size_t)i * 16 + lr] = o;
    }
  }
}

// ------- fused MFMA GEMM: rst = PReLU(hb@Ws + aggb@Wn + b), + partial stats --
// 256 thr (4 waves), BM=128, full N=128, K=128 per source, 16x16x32 bf16 MFMA.
// Wave w: rows w*32..w*32+31 (2 M-frags x 8 N-frags). Tiles padded +8 bf16.
__global__ __launch_bounds__(256) void k_gemm_fused(
    const __hip_bfloat16* __restrict__ hb, const __hip_bfloat16* __restrict__ aggb,
    const __hip_bfloat16* __restrict__ Wst, const __hip_bfloat16* __restrict__ Wnt,
    const float* __restrict__ bias, const float* __restrict__ pw,
    float* __restrict__ rst, float* __restrict__ partial, int n) {
  __shared__ short Ah[128 * 136];
  __shared__ short Aa[128 * 136];
  __shared__ short Bs[128 * 136];
  __shared__ short Bn[128 * 136];
  __shared__ float ls[128], lq[128];
  int t = threadIdx.x;
  int row0 = blockIdx.x * 128;
  if (t < 128) { ls[t] = 0.f; lq[t] = 0.f; }
  for (int ch = t; ch < 2048; ch += 256) {       // 16B chunks: r = ch>>4, col8 = (ch&15)*8
    int r = ch >> 4, c8 = (ch & 15) * 8;
    uint4 va = make_uint4(0, 0, 0, 0), vb = va;
    if (row0 + r < n) {
      va = *(const uint4*)(hb   + (size_t)(row0 + r) * 128 + c8);
      vb = *(const uint4*)(aggb + (size_t)(row0 + r) * 128 + c8);
    }
    *(uint4*)&Ah[r * 136 + c8] = va;
    *(uint4*)&Aa[r * 136 + c8] = vb;
    *(uint4*)&Bs[r * 136 + c8] = *(const uint4*)(Wst + r * 128 + c8);
    *(uint4*)&Bn[r * 136 + c8] = *(const uint4*)(Wnt + r * 128 + c8);
  }
  __syncthreads();
  int w = t >> 6, lane = t & 63;
  int lr = lane & 15, lk = (lane >> 4) * 8;
  f32x4 acc[2][8];
#pragma unroll
  for (int fm = 0; fm < 2; ++fm)
#pragma unroll
    for (int fn = 0; fn < 8; ++fn) acc[fm][fn] = (f32x4){0.f, 0.f, 0.f, 0.f};

  const short* As[2] = {Ah, Aa};
  const short* Bsrc[2] = {Bs, Bn};
#pragma unroll
  for (int s = 0; s < 2; ++s) {
    const short* A = As[s];
    const short* B = Bsrc[s];
#pragma unroll
    for (int ks = 0; ks < 4; ++ks) {
      bf16x8 af[2], bfr[8];
#pragma unroll
      for (int fm = 0; fm < 2; ++fm)
        af[fm] = *(const bf16x8*)&A[(w * 32 + fm * 16 + lr) * 136 + ks * 32 + lk];
#pragma unroll
      for (int fn = 0; fn < 8; ++fn)
        bfr[fn] = *(const bf16x8*)&B[(fn * 16 + lr) * 136 + ks * 32 + lk];
#pragma unroll
      for (int fm = 0; fm < 2; ++fm)
#pragma unroll
        for (int fn = 0; fn < 8; ++fn)
          acc[fm][fn] = __builtin_amdgcn_mfma_f32_16x16x32_bf16(af[fm], bfr[fn], acc[fm][fn], 0, 0, 0);
    }
  }
  // epilogue: bias + PReLU + store fp32 + per-lane stats -> LDS -> partial
  int rb = (lane >> 4) * 4;    // C/D: col = lane&15, row = 4*(lane>>4)+reg  [m89]
  float sacc[8], qacc[8];
#pragma unroll
  for (int fn = 0; fn < 8; ++fn) { sacc[fn] = 0.f; qacc[fn] = 0.f; }
#pragma unroll
  for (int fm = 0; fm < 2; ++fm) {
    int rbase = row0 + w * 32 + fm * 16 + rb;
#pragma unroll
    for (int fn = 0; fn < 8; ++fn) {
      int col = fn * 16 + lr;
      float bb = bias[col], pp = pw[col];
#pragma unroll
      for (int r = 0; r < 4; ++r) {
        int grow = rbase + r;
        if (grow < n) {
          float v = acc[fm][fn][r] + bb;
          v = v > 0.f ? v : pp * v;
          rst[(size_t)grow * 128 + col] = v;
          sacc[fn] += v; qacc[fn] += v * v;
        }
      }
    }
  }
#pragma unroll
  for (int fn = 0; fn < 8; ++fn) {
    int col = fn * 16 + lr;
    atomicAdd(&ls[col], sacc[fn]);
    atomicAdd(&lq[col], qacc[fn]);
  }
  __syncthreads();
  if (t < 128) {
    partial[(size_t)blockIdx.x * 256 + t]       = ls[t];
    partial[(size_t)blockIdx.x * 256 + 128 + t] = lq[t];
  }
}

// ------------- reduce partial stats -> BN scale/shift ------------------------
__global__ __launch_bounds__(1024) void k_bnfin(const float* __restrict__ partial, int nb,
                                                const float* __restrict__ gamma,
                                                const float* __restrict__ beta,
                                                float* __restrict__ ss, int n) {
  __shared__ float red[4][256];
  int t = threadIdx.x, c = t & 255, part = t >> 8;
  float s = 0.f;
  for (int b = part; b < nb; b += 4) s += partial[(size_t)b * 256 + c];
  red[part][c] = s;
  __syncthreads();
  if (part == 0) red[0][c] = red[0][c] + red[1][c] + red[2][c] + red[3][c];
  __syncthreads();
  if (t < 128) {
    float inv_n = 1.0f / (float)n;
    float mu = red[0][t] * inv_n;
    float var = red[0][128 + t] * inv_n - mu * mu;
    float sc = rsqrtf(var + EPS_BN) * gamma[t];
    ss[t] = sc;
    ss[128 + t] = beta[t] - mu * sc;
  }
}

// ------------- BN apply + per-graph pool (fp32) + next-layer bf16 h ----------
__global__ __launch_bounds__(128) void k_bnpool(const float* __restrict__ rst,
                                                __hip_bfloat16* __restrict__ hb,
                                                const float* __restrict__ ss,
                                                const int* __restrict__ gid, float* __restrict__ out,
                                                int l, int n) {
  int t = threadIdx.x;
  float sc = ss[t], sh = ss[128 + t];
  int chunk = (n + gridDim.x - 1) / gridDim.x;
  int i0 = blockIdx.x * chunk;
  int i1 = min(n, i0 + chunk);
  if (i0 >= i1) return;
  int cg = gid[i0];
  float gs = 0.f;
  for (int i = i0; i < i1; ++i) {
    int g = gid[i];
    float x = rst[(size_t)i * 128 + t] * sc + sh;
    hb[(size_t)i * 128 + t] = __float2bfloat16(x);
    if (g != cg) { atomicAdd(&out[cg * 512 + l * 128 + t], gs); gs = 0.f; cg = g; }
    gs += x;
  }
  atomicAdd(&out[cg * 512 + l * 128 + t], gs);
}

// ------------- divide pooled sums by graph node counts -----------------------
__global__ __launch_bounds__(256) void k_div(float* __restrict__ out, const int* __restrict__ gcnt, int m) {
  int i = blockIdx.x * 256 + threadIdx.x;
  if (i < m) {
    int g = i >> 9;
    int c = gcnt[g];
    out[i] *= 1.0f / (float)(c > 0 ? c : 1);
  }
}

extern "C" void kernel_launch(void* const* d_in, const int* in_sizes, int n_in,
                              void* d_out, int out_size, void* d_ws, size_t ws_size,
                              hipStream_t stream) {
  const int*   in_feat = (const int*)d_in[0];
  const int*   src     = (const int*)d_in[1];
  const int*   dst     = (const int*)d_in[2];
  const int*   gid     = (const int*)d_in[3];
  const float* emb     = (const float*)d_in[4];
  const float* Wself   = (const float*)d_in[5];
  const float* Wneigh  = (const float*)d_in[6];
  const float* bvec    = (const float*)d_in[7];
  const float* gamma   = (const float*)d_in[8];
  const float* beta    = (const float*)d_in[9];
  const float* prelu   = (const float*)d_in[10];
  const int N = in_sizes[0];
  const int E = in_sizes[1];
  const int G = out_size / 512;
  float* out = (float*)d_out;
  const int NB = (N + 127) / 128;   // gemm blocks

  char* p = (char*)d_ws;
  size_t off = 0;
  auto take = [&](size_t bytes) { void* r = p + off; off += (bytes + 255) & ~(size_t)255; return r; };
  __hip_bfloat16* hb    = (__hip_bfloat16*)take((size_t)N * 128 * 2);
  __hip_bfloat16* aggb  = (__hip_bfloat16*)take((size_t)N * 128 * 2);
  float*          rst   = (float*)take((size_t)N * 128 * 4);
  __hip_bfloat16* Wst   = (__hip_bfloat16*)take((size_t)4 * 128 * 128 * 2);
  __hip_bfloat16* Wnt   = (__hip_bfloat16*)take((size_t)4 * 128 * 128 * 2);
  float* partial        = (float*)take((size_t)NB * 256 * 4);
  int*   csr_src = (int*)take((size_t)E * 4);
  int*   cnt     = (int*)take((size_t)N * 4);
  int*   rp      = (int*)take((size_t)(N + 1) * 4);
  int*   cursor  = (int*)take((size_t)N * 4);
  float* deg     = (float*)take((size_t)N * 4);
  int*   bs      = (int*)take(512);
  int*   gcnt    = (int*)take(512);
  float* ss      = (float*)take(1024);
  if (off > ws_size) return;

  hipMemsetAsync(cnt, 0, (size_t)N * 4, stream);
  hipMemsetAsync(d_out, 0, (size_t)out_size * 4, stream);

  k_embed<<<(N * 64 + 255) / 256, 256, 0, stream>>>(in_feat, emb, (__hip_bfloat162*)hb, N);
  k_wconv<<<(4 * 128 * 128 + 255) / 256, 256, 0, stream>>>(Wself, Wst, 4 * 128 * 128);
  k_wconv<<<(4 * 128 * 128 + 255) / 256, 256, 0, stream>>>(Wneigh, Wnt, 4 * 128 * 128);
  k_hist<<<(E + 255) / 256, 256, 0, stream>>>(dst, cnt, E);
  k_gcount<<<1, 128, 0, stream>>>(gid, gcnt, N, G);
  int nsb = (N + 1023) / 1024;
  k_scan1<<<nsb, 256, 0, stream>>>(cnt, rp, bs, N);
  k_scan2<<<1, 128, 0, stream>>>(bs, nsb);
  k_scan3<<<(N + 255) / 256, 256, 0, stream>>>(rp, bs, cnt, cursor, deg, N, E);
  k_csr<<<(E + 255) / 256, 256, 0, stream>>>(src, dst, cursor, csr_src, E);

  for (int l = 0; l < 4; ++l) {
    k_agg<<<2048, 256, 0, stream>>>((const uint4*)hb, rp, csr_src, deg,
                                    (uint4*)aggb, N);
    k_gemm_fused<<<NB, 256, 0, stream>>>(hb, aggb, Wst + l * 16384, Wnt + l * 16384,
                                         bvec + l * 128, prelu + l * 128, rst, partial, N);
    k_bnfin<<<1, 1024, 0, stream>>>(partial, NB, gamma + l * 128, beta + l * 128, ss, N);
    k_bnpool<<<2048, 128, 0, stream>>>(rst, hb, ss, gid, out, l, N);
  }
  k_div<<<(out_size + 255) / 256, 256, 0, stream>>>(out, gcnt, out_size);
}